// Round 6
// baseline (426.757 us; speedup 1.0000x reference)
//
#include <hip/hip_runtime.h>
#include <hip/hip_fp16.h>
#include <math.h>

// GraphSAGE 2-layer, N=100000 nodes, E=3200000 edges
// IN=128, H1=32, H2=20, NCLS=10
// Aggregate in OUTPUT feature space; CSR-by-dst via 2-level bucketing;
// fp16 gather tables with 64B rows; per-row lo/hi split by src range so
// each aggregation phase's gather working set (3.2MB) fits per-XCD L2.

#define BSHIFT 7
#define BS_NODES 128          // nodes per bucket
#define PART_TILE 4096        // edges per k_part block

__global__ __launch_bounds__(256) void k_lin1(
    const float* __restrict__ x, const float* __restrict__ W1l,
    const float* __restrict__ W1r, __half* __restrict__ y1,
    float* __restrict__ r1, int n_nodes)
{
    int n = blockIdx.x * 256 + threadIdx.x;
    if (n >= n_nodes) return;
    float accL[32], accR[32];
#pragma unroll
    for (int j = 0; j < 32; ++j) { accL[j] = 0.f; accR[j] = 0.f; }
    const float4* x4 = reinterpret_cast<const float4*>(x) + (size_t)n * 32;
    for (int k4 = 0; k4 < 32; ++k4) {
        float4 xv = x4[k4];
        const float* wl = W1l + k4 * 4 * 32;   // wave-uniform -> scalar loads
        const float* wr = W1r + k4 * 4 * 32;
#pragma unroll
        for (int j = 0; j < 32; ++j) {
            float a = accL[j];
            a = fmaf(xv.x, wl[j],      a);
            a = fmaf(xv.y, wl[32 + j], a);
            a = fmaf(xv.z, wl[64 + j], a);
            a = fmaf(xv.w, wl[96 + j], a);
            accL[j] = a;
            float b = accR[j];
            b = fmaf(xv.x, wr[j],      b);
            b = fmaf(xv.y, wr[32 + j], b);
            b = fmaf(xv.z, wr[64 + j], b);
            b = fmaf(xv.w, wr[96 + j], b);
            accR[j] = b;
        }
    }
    unsigned upk[16];
#pragma unroll
    for (int q = 0; q < 16; ++q) {
        __half2 h = __floats2half2_rn(accL[2*q], accL[2*q+1]);
        upk[q] = *reinterpret_cast<unsigned*>(&h);
    }
    uint4* yo = reinterpret_cast<uint4*>(y1 + (size_t)n * 32);
#pragma unroll
    for (int q = 0; q < 4; ++q)
        yo[q] = make_uint4(upk[4*q], upk[4*q+1], upk[4*q+2], upk[4*q+3]);
    float4* ro = reinterpret_cast<float4*>(r1 + (size_t)n * 32);
#pragma unroll
    for (int q = 0; q < 8; ++q)
        ro[q] = make_float4(accR[q*4], accR[q*4+1], accR[q*4+2], accR[q*4+3]);
}

// ---- CSR build, stage 0 ----
__global__ __launch_bounds__(256) void k_binit(
    int* __restrict__ bcursor, int nb, int capb)
{
    int i = blockIdx.x * 256 + threadIdx.x;
    if (i < nb) bcursor[i] = i * capb;
}

// ---- stage 1: partition edges into per-bucket regions ----
__global__ __launch_bounds__(256) void k_part(
    const int* __restrict__ src, const int* __restrict__ dst,
    int* __restrict__ bcursor, int* __restrict__ pairs,
    int n_edges, int nb)
{
    __shared__ int cnt[1024];
    __shared__ int bbase_l[1024];
    int tid = threadIdx.x;
    int ebeg = blockIdx.x * PART_TILE;
    int eend = ebeg + PART_TILE; if (eend > n_edges) eend = n_edges;
    for (int i = tid; i < nb; i += 256) cnt[i] = 0;
    __syncthreads();
    for (int e = ebeg + tid; e < eend; e += 256)
        atomicAdd(&cnt[dst[e] >> BSHIFT], 1);
    __syncthreads();
    for (int i = tid; i < nb; i += 256) {
        int c = cnt[i];
        if (c > 0) bbase_l[i] = atomicAdd(&bcursor[i], c);
    }
    __syncthreads();
    for (int e = ebeg + tid; e < eend; e += 256) {
        int d = dst[e];
        int b = d >> BSHIFT;
        int slot = atomicSub(&cnt[b], 1) - 1;     // countdown ticket
        pairs[(size_t)bbase_l[b] + slot] = (src[e] << BSHIFT) | (d & (BS_NODES - 1));
    }
}

// ---- stage 2: scan bucket counts ----
__global__ __launch_bounds__(1024) void k_bscan(
    const int* __restrict__ bcursor, int* __restrict__ bbase,
    int* __restrict__ row_ptr, int nb, int capb, int n_nodes)
{
    __shared__ int sc[1024];
    int t = threadIdx.x;
    int c = (t < nb) ? (bcursor[t] - t * capb) : 0;
    sc[t] = c;
    __syncthreads();
    for (int off = 1; off < 1024; off <<= 1) {
        int v = (t >= off) ? sc[t - off] : 0;
        __syncthreads();
        sc[t] += v;
        __syncthreads();
    }
    if (t < nb) bbase[t] = sc[t] - c;   // exclusive
    if (t == 1023) row_ptr[n_nodes] = sc[t];
}

// ---- stage 3: per-bucket fill of row_ptr/midp + eid, rows split lo|hi ----
__global__ __launch_bounds__(256) void k_bfill(
    const int* __restrict__ pairs, const int* __restrict__ bcursor,
    const int* __restrict__ bbase, int* __restrict__ row_ptr,
    int* __restrict__ midp, int* __restrict__ eid,
    int capb, int n_nodes, int half)
{
    __shared__ int cntL[BS_NODES];
    __shared__ int cntH[BS_NODES];
    __shared__ int sc[BS_NODES];
    __shared__ int curL[BS_NODES];
    __shared__ int curH[BS_NODES];
    int b = blockIdx.x;
    int t = threadIdx.x;
    int lo = b * BS_NODES;
    size_t pbeg = (size_t)b * capb;
    int cntE = bcursor[b] - b * capb;
    int base = bbase[b];
    if (t < BS_NODES) { cntL[t] = 0; cntH[t] = 0; }
    __syncthreads();
    for (int i = t; i < cntE; i += 256) {
        int p = pairs[pbeg + i];
        if ((p >> BSHIFT) < half) atomicAdd(&cntL[p & (BS_NODES - 1)], 1);
        else                      atomicAdd(&cntH[p & (BS_NODES - 1)], 1);
    }
    __syncthreads();
    int myc = 0, mycl = 0;
    if (t < BS_NODES) { mycl = cntL[t]; myc = mycl + cntH[t]; sc[t] = myc; }
    __syncthreads();
    for (int off = 1; off < BS_NODES; off <<= 1) {
        int v = (t >= off && t < BS_NODES) ? sc[t - off] : 0;
        __syncthreads();
        if (t < BS_NODES) sc[t] += v;
        __syncthreads();
    }
    if (t < BS_NODES) {
        int excl = sc[t] - myc;
        curL[t] = excl;
        curH[t] = excl + mycl;
        if (lo + t < n_nodes) {
            row_ptr[lo + t] = base + excl;
            midp[lo + t]    = base + excl + mycl;
        }
    }
    __syncthreads();
    for (int i = t; i < cntE; i += 256) {
        int p = pairs[pbeg + i];
        int node = p & (BS_NODES - 1);
        int s = p >> BSHIFT;
        int pos = (s < half) ? atomicAdd(&curL[node], 1) : atomicAdd(&curH[node], 1);
        eid[(size_t)base + pos] = s;
    }
}

// ---- generic gather-sum over [beg,end) of a 64B-row fp16 table ----
__device__ __forceinline__ float gather_sum(
    const int* __restrict__ eid, const __half* __restrict__ tab,
    int beg, int end, int ch)
{
    float s0 = 0.f, s1 = 0.f, s2 = 0.f, s3 = 0.f;
    int i = beg;
    for (; i + 4 <= end; i += 4) {
        int e0 = __builtin_nontemporal_load(&eid[i]);
        int e1 = __builtin_nontemporal_load(&eid[i + 1]);
        int e2 = __builtin_nontemporal_load(&eid[i + 2]);
        int e3 = __builtin_nontemporal_load(&eid[i + 3]);
        s0 += __half2float(tab[(size_t)e0 * 32 + ch]);
        s1 += __half2float(tab[(size_t)e1 * 32 + ch]);
        s2 += __half2float(tab[(size_t)e2 * 32 + ch]);
        s3 += __half2float(tab[(size_t)e3 * 32 + ch]);
    }
    for (; i < end; ++i) {
        int e = __builtin_nontemporal_load(&eid[i]);
        s0 += __half2float(tab[(size_t)e * 32 + ch]);
    }
    return (s0 + s1) + (s2 + s3);
}

// ---- phase a: lo-half gather only, write fp32 partials ----
__global__ __launch_bounds__(256) void k_agga(
    const int* __restrict__ row_ptr, const int* __restrict__ midp,
    const int* __restrict__ eid, const __half* __restrict__ tab,
    float* __restrict__ psum, int n_nodes)
{
    int t = blockIdx.x * 256 + threadIdx.x;
    int n = t >> 5;
    int ch = t & 31;
    if (n >= n_nodes) return;
    float s = gather_sum(eid, tab, row_ptr[n], midp[n], ch);
    __builtin_nontemporal_store(s, &psum[(size_t)n * 32 + ch]);
}

// ---- Layer-1 phase b: hi-half gather + partial, combine, norm, project ----
__global__ __launch_bounds__(256) void k_agg1b(
    const int* __restrict__ row_ptr, const int* __restrict__ midp,
    const int* __restrict__ eid,
    const __half* __restrict__ y1, const float* __restrict__ psum,
    const float* __restrict__ r1, const float* __restrict__ b1,
    const float* __restrict__ W2l, const float* __restrict__ W2r,
    __half* __restrict__ z2, float* __restrict__ r2, int n_nodes)
{
    int t = blockIdx.x * 256 + threadIdx.x;
    int n = t >> 5;
    int ch = t & 31;
    if (n >= n_nodes) return;
    int beg = row_ptr[n], mid = midp[n], end = row_ptr[n + 1];
    float sum = gather_sum(eid, y1, mid, end, ch)
              + __builtin_nontemporal_load(&psum[(size_t)n * 32 + ch]);
    float inv = 1.0f / fmaxf((float)(end - beg), 1.0f);
    float rself = __builtin_nontemporal_load(&r1[(size_t)n * 32 + ch]);
    float v = fmaf(sum, inv, b1[ch] + rself);
    float ss = v * v;
#pragma unroll
    for (int off = 16; off >= 1; off >>= 1) ss += __shfl_xor(ss, off, 32);
    float h = fmaxf(v / fmaxf(sqrtf(ss), 1e-12f), 0.f);
    float accl = 0.f, accr = 0.f;
#pragma unroll 4
    for (int ii = 0; ii < 32; ++ii) {
        float hv = __shfl(h, ii, 32);
        if (ch < 20) {
            accl = fmaf(hv, W2l[ii * 20 + ch], accl);
            accr = fmaf(hv, W2r[ii * 20 + ch], accr);
        }
    }
    z2[(size_t)n * 32 + ch] = __float2half(ch < 20 ? accl : 0.f);
    if (ch < 20) r2[(size_t)n * 20 + ch] = accr;
}

// ---- Layer-2 phase b: hi-half gather + partial, combine, norm, softmax ----
__global__ __launch_bounds__(256) void k_agg2b(
    const int* __restrict__ row_ptr, const int* __restrict__ midp,
    const int* __restrict__ eid,
    const __half* __restrict__ z2, const float* __restrict__ psum,
    const float* __restrict__ r2, const float* __restrict__ b2,
    const float* __restrict__ Wout, const float* __restrict__ bout,
    float* __restrict__ out, int n_nodes)
{
    int t = blockIdx.x * 256 + threadIdx.x;
    int n = t >> 5;
    int ch = t & 31;
    if (n >= n_nodes) return;
    int beg = row_ptr[n], mid = midp[n], end = row_ptr[n + 1];
    bool act = ch < 20;
    float sum = gather_sum(eid, z2, mid, end, ch)
              + __builtin_nontemporal_load(&psum[(size_t)n * 32 + ch]);
    float inv = 1.0f / fmaxf((float)(end - beg), 1.0f);
    float rself = act ? __builtin_nontemporal_load(&r2[(size_t)n * 20 + ch]) : 0.f;
    float v = act ? fmaf(sum, inv, b2[ch] + rself) : 0.f;
    float ss = v * v;
#pragma unroll
    for (int off = 16; off >= 1; off >>= 1) ss += __shfl_xor(ss, off, 32);
    float o = v / fmaxf(sqrtf(ss), 1e-12f);
    float acc = (ch < 10) ? bout[ch] : 0.f;
#pragma unroll 4
    for (int ii = 0; ii < 20; ++ii) {
        float ov = __shfl(o, ii, 32);
        if (ch < 10) acc = fmaf(ov, Wout[ii * 10 + ch], acc);
    }
    float lm = (ch < 10) ? acc : -1e30f;
    float m = lm;
#pragma unroll
    for (int off = 8; off >= 1; off >>= 1) m = fmaxf(m, __shfl_xor(m, off, 16));
    float ex = (ch < 10) ? expf(acc - m) : 0.f;
    float s2r = ex;
#pragma unroll
    for (int off = 8; off >= 1; off >>= 1) s2r += __shfl_xor(s2r, off, 16);
    if (ch < 10) out[(size_t)n * 10 + ch] = ex / s2r;
}

extern "C" void kernel_launch(void* const* d_in, const int* in_sizes, int n_in,
                              void* d_out, int out_size, void* d_ws, size_t ws_size,
                              hipStream_t stream)
{
    const float* x    = (const float*)d_in[0];
    const int*   ei   = (const int*)d_in[1];
    const float* W1l  = (const float*)d_in[2];
    const float* b1   = (const float*)d_in[3];
    const float* W1r  = (const float*)d_in[4];
    const float* W2l  = (const float*)d_in[5];
    const float* b2   = (const float*)d_in[6];
    const float* W2r  = (const float*)d_in[7];
    const float* Wout = (const float*)d_in[8];
    const float* bout = (const float*)d_in[9];
    float* out = (float*)d_out;

    int n_nodes = in_sizes[0] / 128;
    int n_edges = in_sizes[1] / 2;
    const int* src = ei;
    const int* dst = ei + n_edges;
    int half = n_nodes >> 1;

    int nb = (n_nodes + BS_NODES - 1) / BS_NODES;   // 782 (<= 1024)
    double mean = (double)n_edges / nb;
    int capb = (int)(mean + 8.0 * sqrt(mean) + 64.0);
    capb = (capb + 63) & ~63;

    // workspace layout
    int* bcursor = (int*)d_ws;                          // nb
    int* bbase   = bcursor + ((nb + 2 + 3) & ~3);       // nb
    int* row_ptr = bbase + ((nb + 3) & ~3);             // n_nodes+1
    int* midp    = row_ptr + (((n_nodes + 1) + 3) & ~3);// n_nodes
    int* eid     = midp + ((n_nodes + 3) & ~3);         // n_edges
    int* pairs   = eid + (((size_t)n_edges + 3) & ~(size_t)3);  // nb*capb

    // fp16 gather tables; y1 aliases pairs (pairs dead before k_lin1 runs)
    __half* y1  = (__half*)pairs;                        // N*32 halfs (64B rows)
    float*  r1  = (float*)(y1 + (size_t)n_nodes * 32);   // N*32 f32
    __half* z2  = (__half*)(r1 + (size_t)n_nodes * 32);  // N*32 halfs (20 used)
    float*  r2  = (float*)(z2 + (size_t)n_nodes * 32);   // N*20 f32
    float*  psum = r2 + (size_t)n_nodes * 20;            // N*32 f32 partials

    int nb_part = (n_edges + PART_TILE - 1) / PART_TILE;
    int nb_node = (n_nodes + 255) / 256;
    int nb_grp  = ((n_nodes * 32) + 255) / 256;

    k_binit<<<(nb + 255) / 256, 256, 0, stream>>>(bcursor, nb, capb);
    k_part<<<nb_part, 256, 0, stream>>>(src, dst, bcursor, pairs, n_edges, nb);
    k_bscan<<<1, 1024, 0, stream>>>(bcursor, bbase, row_ptr, nb, capb, n_nodes);
    k_bfill<<<nb, 256, 0, stream>>>(pairs, bcursor, bbase, row_ptr, midp, eid,
                                    capb, n_nodes, half);
    k_lin1<<<nb_node, 256, 0, stream>>>(x, W1l, W1r, y1, r1, n_nodes);
    k_agga<<<nb_grp, 256, 0, stream>>>(row_ptr, midp, eid, y1, psum, n_nodes);
    k_agg1b<<<nb_grp, 256, 0, stream>>>(row_ptr, midp, eid, y1, psum, r1, b1,
                                        W2l, W2r, z2, r2, n_nodes);
    k_agga<<<nb_grp, 256, 0, stream>>>(row_ptr, midp, eid, z2, psum, n_nodes);
    k_agg2b<<<nb_grp, 256, 0, stream>>>(row_ptr, midp, eid, z2, psum, r2, b2,
                                        Wout, bout, out, n_nodes);
}

// Round 7
// 330.401 us; speedup vs baseline: 1.2916x; 1.2916x over previous
//
#include <hip/hip_runtime.h>
#include <hip/hip_fp16.h>
#include <math.h>

// GraphSAGE 2-layer, N=100000 nodes, E=3200000 edges
// IN=128, H1=32, H2=20, NCLS=10
// Aggregate in OUTPUT feature space; CSR-by-dst via 2-level bucketing;
// fp16 gather tables with 64B rows; gather loop unrolled x8 (8 independent
// chains in flight); eid index loads CACHED (NT on eid was a ~900cy serial
// stall at the head of every iteration -- r6 post-mortem).

#define BSHIFT 7
#define BS_NODES 128          // nodes per bucket
#define PART_TILE 4096        // edges per k_part block

__global__ __launch_bounds__(256) void k_lin1(
    const float* __restrict__ x, const float* __restrict__ W1l,
    const float* __restrict__ W1r, __half* __restrict__ y1,
    float* __restrict__ r1, int n_nodes)
{
    int n = blockIdx.x * 256 + threadIdx.x;
    if (n >= n_nodes) return;
    float accL[32], accR[32];
#pragma unroll
    for (int j = 0; j < 32; ++j) { accL[j] = 0.f; accR[j] = 0.f; }
    const float4* x4 = reinterpret_cast<const float4*>(x) + (size_t)n * 32;
    for (int k4 = 0; k4 < 32; ++k4) {
        float4 xv = x4[k4];
        const float* wl = W1l + k4 * 4 * 32;   // wave-uniform -> scalar loads
        const float* wr = W1r + k4 * 4 * 32;
#pragma unroll
        for (int j = 0; j < 32; ++j) {
            float a = accL[j];
            a = fmaf(xv.x, wl[j],      a);
            a = fmaf(xv.y, wl[32 + j], a);
            a = fmaf(xv.z, wl[64 + j], a);
            a = fmaf(xv.w, wl[96 + j], a);
            accL[j] = a;
            float b = accR[j];
            b = fmaf(xv.x, wr[j],      b);
            b = fmaf(xv.y, wr[32 + j], b);
            b = fmaf(xv.z, wr[64 + j], b);
            b = fmaf(xv.w, wr[96 + j], b);
            accR[j] = b;
        }
    }
    unsigned upk[16];
#pragma unroll
    for (int q = 0; q < 16; ++q) {
        __half2 h = __floats2half2_rn(accL[2*q], accL[2*q+1]);
        upk[q] = *reinterpret_cast<unsigned*>(&h);
    }
    uint4* yo = reinterpret_cast<uint4*>(y1 + (size_t)n * 32);
#pragma unroll
    for (int q = 0; q < 4; ++q)
        yo[q] = make_uint4(upk[4*q], upk[4*q+1], upk[4*q+2], upk[4*q+3]);
    float4* ro = reinterpret_cast<float4*>(r1 + (size_t)n * 32);
#pragma unroll
    for (int q = 0; q < 8; ++q)
        ro[q] = make_float4(accR[q*4], accR[q*4+1], accR[q*4+2], accR[q*4+3]);
}

// ---- CSR build, stage 0 ----
__global__ __launch_bounds__(256) void k_binit(
    int* __restrict__ bcursor, int nb, int capb)
{
    int i = blockIdx.x * 256 + threadIdx.x;
    if (i < nb) bcursor[i] = i * capb;
}

// ---- stage 1: partition edges into per-bucket regions ----
__global__ __launch_bounds__(256) void k_part(
    const int* __restrict__ src, const int* __restrict__ dst,
    int* __restrict__ bcursor, int* __restrict__ pairs,
    int n_edges, int nb)
{
    __shared__ int cnt[1024];
    __shared__ int bbase_l[1024];
    int tid = threadIdx.x;
    int ebeg = blockIdx.x * PART_TILE;
    int eend = ebeg + PART_TILE; if (eend > n_edges) eend = n_edges;
    for (int i = tid; i < nb; i += 256) cnt[i] = 0;
    __syncthreads();
    for (int e = ebeg + tid; e < eend; e += 256)
        atomicAdd(&cnt[dst[e] >> BSHIFT], 1);
    __syncthreads();
    for (int i = tid; i < nb; i += 256) {
        int c = cnt[i];
        if (c > 0) bbase_l[i] = atomicAdd(&bcursor[i], c);
    }
    __syncthreads();
    for (int e = ebeg + tid; e < eend; e += 256) {
        int d = dst[e];
        int b = d >> BSHIFT;
        int slot = atomicSub(&cnt[b], 1) - 1;     // countdown ticket
        pairs[(size_t)bbase_l[b] + slot] = (src[e] << BSHIFT) | (d & (BS_NODES - 1));
    }
}

// ---- stage 2: scan bucket counts ----
__global__ __launch_bounds__(1024) void k_bscan(
    const int* __restrict__ bcursor, int* __restrict__ bbase,
    int* __restrict__ row_ptr, int nb, int capb, int n_nodes)
{
    __shared__ int sc[1024];
    int t = threadIdx.x;
    int c = (t < nb) ? (bcursor[t] - t * capb) : 0;
    sc[t] = c;
    __syncthreads();
    for (int off = 1; off < 1024; off <<= 1) {
        int v = (t >= off) ? sc[t - off] : 0;
        __syncthreads();
        sc[t] += v;
        __syncthreads();
    }
    if (t < nb) bbase[t] = sc[t] - c;   // exclusive
    if (t == 1023) row_ptr[n_nodes] = sc[t];
}

// ---- stage 3: per-bucket fill of row_ptr + eid ----
__global__ __launch_bounds__(256) void k_bfill(
    const int* __restrict__ pairs, const int* __restrict__ bcursor,
    const int* __restrict__ bbase, int* __restrict__ row_ptr,
    int* __restrict__ eid, int capb, int n_nodes)
{
    __shared__ int cnt128[BS_NODES];
    __shared__ int sc[BS_NODES];
    __shared__ int cur[BS_NODES];
    int b = blockIdx.x;
    int t = threadIdx.x;
    int lo = b * BS_NODES;
    size_t pbeg = (size_t)b * capb;
    int cntE = bcursor[b] - b * capb;
    int base = bbase[b];
    if (t < BS_NODES) cnt128[t] = 0;
    __syncthreads();
    for (int i = t; i < cntE; i += 256)
        atomicAdd(&cnt128[pairs[pbeg + i] & (BS_NODES - 1)], 1);
    __syncthreads();
    int myc = 0;
    if (t < BS_NODES) { myc = cnt128[t]; sc[t] = myc; }
    __syncthreads();
    for (int off = 1; off < BS_NODES; off <<= 1) {
        int v = (t >= off && t < BS_NODES) ? sc[t - off] : 0;
        __syncthreads();
        if (t < BS_NODES) sc[t] += v;
        __syncthreads();
    }
    if (t < BS_NODES) {
        int excl = sc[t] - myc;
        cur[t] = excl;
        if (lo + t < n_nodes) row_ptr[lo + t] = base + excl;
    }
    __syncthreads();
    for (int i = t; i < cntE; i += 256) {
        int p = pairs[pbeg + i];
        int pos = atomicAdd(&cur[p & (BS_NODES - 1)], 1);
        eid[(size_t)base + pos] = p >> BSHIFT;
    }
}

// ---- gather-sum over [beg,end): 8 independent chains, cached eid loads ----
__device__ __forceinline__ float gather_sum(
    const int* __restrict__ eid, const __half* __restrict__ tab,
    int beg, int end, int ch)
{
    float s0 = 0.f, s1 = 0.f, s2 = 0.f, s3 = 0.f;
    float s4 = 0.f, s5 = 0.f, s6 = 0.f, s7 = 0.f;
    int i = beg;
    for (; i + 8 <= end; i += 8) {
        int e0 = eid[i];
        int e1 = eid[i + 1];
        int e2 = eid[i + 2];
        int e3 = eid[i + 3];
        int e4 = eid[i + 4];
        int e5 = eid[i + 5];
        int e6 = eid[i + 6];
        int e7 = eid[i + 7];
        s0 += __half2float(tab[(size_t)e0 * 32 + ch]);
        s1 += __half2float(tab[(size_t)e1 * 32 + ch]);
        s2 += __half2float(tab[(size_t)e2 * 32 + ch]);
        s3 += __half2float(tab[(size_t)e3 * 32 + ch]);
        s4 += __half2float(tab[(size_t)e4 * 32 + ch]);
        s5 += __half2float(tab[(size_t)e5 * 32 + ch]);
        s6 += __half2float(tab[(size_t)e6 * 32 + ch]);
        s7 += __half2float(tab[(size_t)e7 * 32 + ch]);
    }
    for (; i + 4 <= end; i += 4) {
        int e0 = eid[i];
        int e1 = eid[i + 1];
        int e2 = eid[i + 2];
        int e3 = eid[i + 3];
        s0 += __half2float(tab[(size_t)e0 * 32 + ch]);
        s1 += __half2float(tab[(size_t)e1 * 32 + ch]);
        s2 += __half2float(tab[(size_t)e2 * 32 + ch]);
        s3 += __half2float(tab[(size_t)e3 * 32 + ch]);
    }
    for (; i < end; ++i) {
        int e = eid[i];
        s0 += __half2float(tab[(size_t)e * 32 + ch]);
    }
    return ((s0 + s1) + (s2 + s3)) + ((s4 + s5) + (s6 + s7));
}

// ---- Layer 1: gather-sum fp16 y1, combine, normalize, relu, project ----
__global__ __launch_bounds__(256) void k_agg1(
    const int* __restrict__ row_ptr, const int* __restrict__ eid,
    const __half* __restrict__ y1, const float* __restrict__ r1,
    const float* __restrict__ b1, const float* __restrict__ W2l,
    const float* __restrict__ W2r,
    __half* __restrict__ z2, float* __restrict__ r2, int n_nodes)
{
    int t = blockIdx.x * 256 + threadIdx.x;
    int n = t >> 5;
    int ch = t & 31;
    if (n >= n_nodes) return;
    int beg = row_ptr[n], end = row_ptr[n + 1];
    float sum = gather_sum(eid, y1, beg, end, ch);
    float inv = 1.0f / fmaxf((float)(end - beg), 1.0f);
    float v = fmaf(sum, inv, b1[ch] + r1[(size_t)n * 32 + ch]);
    float ss = v * v;
#pragma unroll
    for (int off = 16; off >= 1; off >>= 1) ss += __shfl_xor(ss, off, 32);
    float h = fmaxf(v / fmaxf(sqrtf(ss), 1e-12f), 0.f);
    float accl = 0.f, accr = 0.f;
#pragma unroll 4
    for (int ii = 0; ii < 32; ++ii) {
        float hv = __shfl(h, ii, 32);
        if (ch < 20) {
            accl = fmaf(hv, W2l[ii * 20 + ch], accl);
            accr = fmaf(hv, W2r[ii * 20 + ch], accr);
        }
    }
    z2[(size_t)n * 32 + ch] = __float2half(ch < 20 ? accl : 0.f);
    if (ch < 20) r2[(size_t)n * 20 + ch] = accr;
}

// ---- Layer 2: gather-sum fp16 z2, combine, normalize, W_out, softmax ----
__global__ __launch_bounds__(256) void k_agg2(
    const int* __restrict__ row_ptr, const int* __restrict__ eid,
    const __half* __restrict__ z2, const float* __restrict__ r2,
    const float* __restrict__ b2, const float* __restrict__ Wout,
    const float* __restrict__ bout,
    float* __restrict__ out, int n_nodes)
{
    int t = blockIdx.x * 256 + threadIdx.x;
    int n = t >> 5;
    int ch = t & 31;
    if (n >= n_nodes) return;
    int beg = row_ptr[n], end = row_ptr[n + 1];
    bool act = ch < 20;
    float sum = gather_sum(eid, z2, beg, end, ch);
    float inv = 1.0f / fmaxf((float)(end - beg), 1.0f);
    float v = act ? fmaf(sum, inv, b2[ch] + r2[(size_t)n * 20 + ch]) : 0.f;
    float ss = v * v;
#pragma unroll
    for (int off = 16; off >= 1; off >>= 1) ss += __shfl_xor(ss, off, 32);
    float o = v / fmaxf(sqrtf(ss), 1e-12f);
    float acc = (ch < 10) ? bout[ch] : 0.f;
#pragma unroll 4
    for (int ii = 0; ii < 20; ++ii) {
        float ov = __shfl(o, ii, 32);
        if (ch < 10) acc = fmaf(ov, Wout[ii * 10 + ch], acc);
    }
    float lm = (ch < 10) ? acc : -1e30f;
    float m = lm;
#pragma unroll
    for (int off = 8; off >= 1; off >>= 1) m = fmaxf(m, __shfl_xor(m, off, 16));
    float ex = (ch < 10) ? expf(acc - m) : 0.f;
    float s2r = ex;
#pragma unroll
    for (int off = 8; off >= 1; off >>= 1) s2r += __shfl_xor(s2r, off, 16);
    if (ch < 10) out[(size_t)n * 10 + ch] = ex / s2r;
}

extern "C" void kernel_launch(void* const* d_in, const int* in_sizes, int n_in,
                              void* d_out, int out_size, void* d_ws, size_t ws_size,
                              hipStream_t stream)
{
    const float* x    = (const float*)d_in[0];
    const int*   ei   = (const int*)d_in[1];
    const float* W1l  = (const float*)d_in[2];
    const float* b1   = (const float*)d_in[3];
    const float* W1r  = (const float*)d_in[4];
    const float* W2l  = (const float*)d_in[5];
    const float* b2   = (const float*)d_in[6];
    const float* W2r  = (const float*)d_in[7];
    const float* Wout = (const float*)d_in[8];
    const float* bout = (const float*)d_in[9];
    float* out = (float*)d_out;

    int n_nodes = in_sizes[0] / 128;
    int n_edges = in_sizes[1] / 2;
    const int* src = ei;
    const int* dst = ei + n_edges;

    int nb = (n_nodes + BS_NODES - 1) / BS_NODES;   // 782 (<= 1024)
    double mean = (double)n_edges / nb;
    int capb = (int)(mean + 8.0 * sqrt(mean) + 64.0);
    capb = (capb + 63) & ~63;

    // workspace layout
    int* bcursor = (int*)d_ws;                          // nb
    int* bbase   = bcursor + ((nb + 2 + 3) & ~3);       // nb
    int* row_ptr = bbase + ((nb + 3) & ~3);             // n_nodes+1
    int* eid     = row_ptr + (((n_nodes + 1) + 3) & ~3);// n_edges
    int* pairs   = eid + (((size_t)n_edges + 3) & ~(size_t)3);  // nb*capb

    // fp16 gather tables; y1 aliases pairs (pairs dead before k_lin1 runs)
    __half* y1 = (__half*)pairs;                        // N*32 halfs (64B rows)
    float*  r1 = (float*)(y1 + (size_t)n_nodes * 32);   // N*32 f32
    __half* z2 = (__half*)(r1 + (size_t)n_nodes * 32);  // N*32 halfs (20 used)
    float*  r2 = (float*)(z2 + (size_t)n_nodes * 32);   // N*20 f32

    int nb_part = (n_edges + PART_TILE - 1) / PART_TILE;
    int nb_node = (n_nodes + 255) / 256;
    int nb_grp  = ((n_nodes * 32) + 255) / 256;

    k_binit<<<(nb + 255) / 256, 256, 0, stream>>>(bcursor, nb, capb);
    k_part<<<nb_part, 256, 0, stream>>>(src, dst, bcursor, pairs, n_edges, nb);
    k_bscan<<<1, 1024, 0, stream>>>(bcursor, bbase, row_ptr, nb, capb, n_nodes);
    k_bfill<<<nb, 256, 0, stream>>>(pairs, bcursor, bbase, row_ptr, eid, capb, n_nodes);
    k_lin1<<<nb_node, 256, 0, stream>>>(x, W1l, W1r, y1, r1, n_nodes);
    k_agg1<<<nb_grp, 256, 0, stream>>>(row_ptr, eid, y1, r1, b1, W2l, W2r, z2, r2, n_nodes);
    k_agg2<<<nb_grp, 256, 0, stream>>>(row_ptr, eid, z2, r2, b2, Wout, bout, out, n_nodes);
}